// Round 7
// baseline (274.847 us; speedup 1.0000x reference)
//
#include <hip/hip_runtime.h>
#include <math.h>

#define D_MODEL   128
#define NUM_HEADS 8
#define DK        16
#define NUM_NODES 207
#define SEQ_LEN   12
#define BATCH     4
#define L_TOTAL   (SEQ_LEN * NUM_NODES)   // 2484
#define L_PAD     2496                    // 39*64, 78*32
#define BL        (BATCH * L_TOTAL)       // 9936
#define KHALF     1248                    // L_PAD / 2

typedef short v4s __attribute__((ext_vector_type(4)));
typedef float v4f __attribute__((ext_vector_type(4)));

// Device pass: real MFMA builtin. Host pass: inert stub (parsed, never executed).
#if defined(__HIP_DEVICE_COMPILE__)
#define MFMA16(a, b, c) __builtin_amdgcn_mfma_f32_16x16x16bf16_1k(a, b, c, 0, 0, 0)
#else
#define MFMA16(a, b, c) (c)
#endif
#define EXP2F(x) exp2f(x)

// float -> bf16 (round to nearest even), pure bit ops (finite inputs only)
static __device__ __forceinline__ unsigned short f2bf(float f) {
    unsigned u = __builtin_bit_cast(unsigned, f);
    unsigned rnd = 0x7fffu + ((u >> 16) & 1u);
    return (unsigned short)((u + rnd) >> 16);
}
static __device__ __forceinline__ unsigned pk2bf(float a, float b) {
    return (unsigned)f2bf(a) | ((unsigned)f2bf(b) << 16);
}

// msmQ[nq][k] = 0.25 * log2(e) * sigmoid(tm) * sigmoid(sm[nq][k % 207]), k in [0, L_PAD)
__global__ void mask_prep_kernel(const float* __restrict__ tmask,
                                 const float* __restrict__ smask,
                                 float* __restrict__ msmQ) {
    int idx = blockIdx.x * 256 + threadIdx.x;
    if (idx >= NUM_NODES * L_PAD) return;
    int nq = idx / L_PAD;
    int k  = idx - nq * L_PAD;
    int nk = k % NUM_NODES;
    float tm = 1.0f / (1.0f + __expf(-tmask[0]));
    float sm = 1.0f / (1.0f + __expf(-smask[nq * NUM_NODES + nk]));
    msmQ[idx] = 0.25f * 1.4426950408889634f * tm * sm;
}

// QKV projection, fp32 compute -> bf16 stores.
// Qb,Kb: [bh][l_pad][16] bf16;  VbT: [bh][d=16][l_pad] bf16.
__global__ __launch_bounds__(128) void qkv_proj_kernel(
    const float* __restrict__ x,
    const float* __restrict__ Wq, const float* __restrict__ bq,
    const float* __restrict__ Wk, const float* __restrict__ bk,
    const float* __restrict__ Wv, const float* __restrict__ bv,
    short* __restrict__ Qb, short* __restrict__ Kb, short* __restrict__ VbT)
{
    __shared__ float xs[16][D_MODEL];
    const int t = threadIdx.x;
    const int row0 = blockIdx.x * 16;
    const int b  = row0 / L_PAD;
    const int l0 = row0 - b * L_PAD;
    #pragma unroll
    for (int r = 0; r < 16; ++r) {
        int l = l0 + r;
        xs[r][t] = (l < L_TOTAL) ? x[((size_t)b * L_TOTAL + l) * D_MODEL + t] : 0.f;
    }
    __syncthreads();

    float aq[16], ak[16], av[16];
    #pragma unroll
    for (int r = 0; r < 16; ++r) { aq[r] = 0.f; ak[r] = 0.f; av[r] = 0.f; }

    for (int i = 0; i < D_MODEL; ++i) {
        float wq = Wq[i * D_MODEL + t];
        float wk = Wk[i * D_MODEL + t];
        float wv = Wv[i * D_MODEL + t];
        #pragma unroll
        for (int r = 0; r < 16; ++r) {
            float xv = xs[r][i];
            aq[r] += xv * wq;
            ak[r] += xv * wk;
            av[r] += xv * wv;
        }
    }

    const float bqv = bq[t], bkv = bk[t], bvv = bv[t];
    const int h = t >> 4, d = t & 15;
    const int bh = b * NUM_HEADS + h;

    #pragma unroll
    for (int r = 0; r < 16; ++r) {
        size_t o = ((size_t)bh * L_PAD + (l0 + r)) * DK + d;
        Qb[o] = (short)f2bf(aq[r] + bqv);
        Kb[o] = (short)f2bf(ak[r] + bkv);
    }
    {
        short* vp = VbT + ((size_t)bh * DK + d) * L_PAD + l0;
        unsigned* vp4 = (unsigned*)vp;
        #pragma unroll
        for (int j = 0; j < 8; ++j)
            vp4[j] = pk2bf(av[2 * j] + bvv, av[2 * j + 1] + bvv);
    }
}

// MFMA attention, v2: block = 8 waves (512 thr). Wave w: q-tile (w>>1), key-half (w&1).
// Swapped QK^T (S^T = K*Q^T); register double-buffer of (K,V,mask) subtiles.
// K-halves merged via LDS (no online max -> plain adds of unnormalized ctx/ssum).
__global__ __launch_bounds__(512) void attn_mfma_kernel(
    const short* __restrict__ Qb, const short* __restrict__ Kb,
    const short* __restrict__ VbT, const float* __restrict__ msmQ,
    float* __restrict__ Ctx)
{
    __shared__ float ctxs[4][64][4];
    __shared__ float ssum[4][64];

    const int tid = threadIdx.x;
    const int l = tid & 63, w = tid >> 6;
    const int qt = w >> 1, kh = w & 1;
    const int r = l & 15, g = l >> 4;
    const int bh = blockIdx.y, b = bh >> 3, h = bh & 7;
    const int q0w = blockIdx.x * 64 + qt * 16;

    const short* Kp = Kb + (size_t)bh * L_PAD * DK;
    const short* Vp = VbT + ((size_t)bh * DK + r) * L_PAD;

    int qload = q0w + r;
    if (qload > L_TOTAL - 1) qload = L_TOTAL - 1;          // clamp pad queries
    const v4s qf = *(const v4s*)(Qb + ((size_t)bh * L_PAD + qload) * DK + 4 * g);
    const float* mp = msmQ + (size_t)((q0w + r) % NUM_NODES) * L_PAD;

    v4f ctx = {0.f, 0.f, 0.f, 0.f};
    float ss0 = 0.f, ss1 = 0.f, ss2 = 0.f, ss3 = 0.f;

#define LOADS(K_SUB, kf, vf, m4) do {                                          \
    kf = *(const v4s*)(Kp + (size_t)((K_SUB) + r) * DK + 4 * g);               \
    vf = *(const v4s*)(Vp + (K_SUB) + 4 * g);                                  \
    m4 = *(const float4*)(mp + (K_SUB) + 4 * g);                               \
} while (0)

#define COMPUTE(kf, vf, m4, MASKED, KIDX) do {                                 \
    v4f z = {0.f, 0.f, 0.f, 0.f};                                              \
    v4f sacc = MFMA16(kf, qf, z);                                              \
    float p0 = EXP2F(sacc[0] * m4.x);                                          \
    float p1 = EXP2F(sacc[1] * m4.y);                                          \
    float p2 = EXP2F(sacc[2] * m4.z);                                          \
    float p3 = EXP2F(sacc[3] * m4.w);                                          \
    if (MASKED) {                                                              \
        int kb0 = (KIDX) + 4 * g;                                              \
        if (kb0 + 0 >= L_TOTAL) p0 = 0.f;                                      \
        if (kb0 + 1 >= L_TOTAL) p1 = 0.f;                                      \
        if (kb0 + 2 >= L_TOTAL) p2 = 0.f;                                      \
        if (kb0 + 3 >= L_TOTAL) p3 = 0.f;                                      \
    }                                                                          \
    ss0 += p0; ss1 += p1; ss2 += p2; ss3 += p3;                                \
    unsigned plo = pk2bf(p0, p1);                                              \
    unsigned phi = pk2bf(p2, p3);                                              \
    v4s pf = __builtin_bit_cast(v4s, ((unsigned long long)phi << 32) | plo);   \
    ctx = MFMA16(pf, vf, ctx);                                                 \
} while (0)

    const int kbase = kh * KHALF;
    v4s kfA, vfA, kfB, vfB;
    float4 m4A, m4B;
    LOADS(kbase, kfA, vfA, m4A);
    int ksub = kbase;
    for (int it = 0; it < 77; ++it) {                      // 78 subtiles per half
        LOADS(ksub + 16, kfB, vfB, m4B);
        COMPUTE(kfA, vfA, m4A, false, 0);
        kfA = kfB; vfA = vfB; m4A = m4B;
        ksub += 16;
    }
    // last subtile: keys [kbase+1232, kbase+1248); only the kh=1 tail crosses L_TOTAL
    COMPUTE(kfA, vfA, m4A, true, ksub);
#undef LOADS
#undef COMPUTE

    // intra-wave row sums: combine the 4 lane-groups -> uniform per r
    float s = (ss0 + ss1) + (ss2 + ss3);
    s += __shfl_xor(s, 16);
    s += __shfl_xor(s, 32);

    // merge the two key-halves
    if (kh == 1) {
        ctxs[qt][l][0] = ctx[0]; ctxs[qt][l][1] = ctx[1];
        ctxs[qt][l][2] = ctx[2]; ctxs[qt][l][3] = ctx[3];
        ssum[qt][l] = s;
    }
    __syncthreads();
    if (kh == 0) {
        ctx[0] += ctxs[qt][l][0]; ctx[1] += ctxs[qt][l][1];
        ctx[2] += ctxs[qt][l][2]; ctx[3] += ctxs[qt][l][3];
        s += ssum[qt][l];
        float inv = 1.0f / s;
        #pragma unroll
        for (int i = 0; i < 4; ++i) {
            int q = q0w + 4 * g + i;
            float iv = __shfl(inv, 4 * g + i);
            if (q < L_TOTAL)
                Ctx[((size_t)b * L_TOTAL + q) * D_MODEL + h * DK + r] = ctx[i] * iv;
        }
    }
}

// Output projection: context (9936x128) @ Wo + bo -> out (fp32)
__global__ __launch_bounds__(128) void out_proj_kernel(
    const float* __restrict__ ctxin,
    const float* __restrict__ Wo, const float* __restrict__ bo,
    float* __restrict__ out)
{
    __shared__ float xs[16][D_MODEL];
    const int t = threadIdx.x;
    const int row0 = blockIdx.x * 16;
    #pragma unroll
    for (int r = 0; r < 16; ++r)
        xs[r][t] = ctxin[(size_t)(row0 + r) * D_MODEL + t];
    __syncthreads();

    float acc[16];
    #pragma unroll
    for (int r = 0; r < 16; ++r) acc[r] = 0.f;

    for (int i = 0; i < D_MODEL; ++i) {
        float wv = Wo[i * D_MODEL + t];
        #pragma unroll
        for (int r = 0; r < 16; ++r) acc[r] += xs[r][i] * wv;
    }

    float bv = bo[t];
    #pragma unroll
    for (int r = 0; r < 16; ++r)
        out[(size_t)(row0 + r) * D_MODEL + t] = acc[r] + bv;
}

extern "C" void kernel_launch(void* const* d_in, const int* in_sizes, int n_in,
                              void* d_out, int out_size, void* d_ws, size_t ws_size,
                              hipStream_t stream) {
    const float* x     = (const float*)d_in[0];
    const float* Wq    = (const float*)d_in[1];
    const float* bq    = (const float*)d_in[2];
    const float* Wk    = (const float*)d_in[3];
    const float* bk    = (const float*)d_in[4];
    const float* Wv    = (const float*)d_in[5];
    const float* bv    = (const float*)d_in[6];
    const float* Wo    = (const float*)d_in[7];
    const float* bo    = (const float*)d_in[8];
    const float* tmask = (const float*)d_in[9];
    const float* smask = (const float*)d_in[10];
    float* out = (float*)d_out;

    // workspace layout (~14.8 MB)
    char* ws = (char*)d_ws;
    size_t o = 0;
    float* msmQ = (float*)(ws + o); o += (size_t)NUM_NODES * L_PAD * 4;          // 2,066,688
    const size_t qk_bytes = (size_t)BATCH * NUM_HEADS * L_PAD * DK * 2;          // 2,555,904
    short* Qb  = (short*)(ws + o); o += qk_bytes;
    short* Kb  = (short*)(ws + o); o += qk_bytes;
    short* VbT = (short*)(ws + o); o += qk_bytes;
    float* Ctx = (float*)(ws + o); o += (size_t)BL * D_MODEL * 4;                // 5,087,232
    (void)ws_size; (void)in_sizes; (void)n_in; (void)out_size;

    mask_prep_kernel<<<(NUM_NODES * L_PAD + 255) / 256, 256, 0, stream>>>(tmask, smask, msmQ);
    qkv_proj_kernel<<<(BATCH * L_PAD) / 16, 128, 0, stream>>>(x, Wq, bq, Wk, bk, Wv, bv, Qb, Kb, VbT);
    attn_mfma_kernel<<<dim3(L_PAD / 64, BATCH * NUM_HEADS), 512, 0, stream>>>(Qb, Kb, VbT, msmQ, Ctx);
    out_proj_kernel<<<BL / 16, 128, 0, stream>>>(Ctx, Wo, bo, out);
}

// Round 8
// 194.570 us; speedup vs baseline: 1.4126x; 1.4126x over previous
//
#include <hip/hip_runtime.h>
#include <math.h>

#define D_MODEL   128
#define NUM_HEADS 8
#define DK        16
#define NUM_NODES 207
#define SEQ_LEN   12
#define BATCH     4
#define L_TOTAL   (SEQ_LEN * NUM_NODES)   // 2484
#define L_PAD     2496                    // 39*64, 78*32
#define BL        (BATCH * L_TOTAL)       // 9936
#define KHALF     1248                    // L_PAD / 2
#define MSTRIDE   211                     // odd stride -> <=3-way LDS bank aliasing

typedef short v4s __attribute__((ext_vector_type(4)));
typedef float v4f __attribute__((ext_vector_type(4)));

// Device pass: real MFMA builtin. Host pass: inert stub (parsed, never executed).
#if defined(__HIP_DEVICE_COMPILE__)
#define MFMA16(a, b, c) __builtin_amdgcn_mfma_f32_16x16x16bf16_1k(a, b, c, 0, 0, 0)
#else
#define MFMA16(a, b, c) (c)
#endif
#define EXP2F(x) exp2f(x)

// float -> bf16 (round to nearest even), pure bit ops (finite inputs only)
static __device__ __forceinline__ unsigned short f2bf(float f) {
    unsigned u = __builtin_bit_cast(unsigned, f);
    unsigned rnd = 0x7fffu + ((u >> 16) & 1u);
    return (unsigned short)((u + rnd) >> 16);
}
static __device__ __forceinline__ unsigned pk2bf(float a, float b) {
    return (unsigned)f2bf(a) | ((unsigned)f2bf(b) << 16);
}

// msmN[nq][nk] = 0.25 * log2(e) * sigmoid(tm) * sigmoid(sm[nq][nk]) -- raw 207x207
__global__ void mask_prep_kernel(const float* __restrict__ tmask,
                                 const float* __restrict__ smask,
                                 float* __restrict__ msmN) {
    int idx = blockIdx.x * 256 + threadIdx.x;
    if (idx >= NUM_NODES * NUM_NODES) return;
    float tm = 1.0f / (1.0f + __expf(-tmask[0]));
    float sm = 1.0f / (1.0f + __expf(-smask[idx]));
    msmN[idx] = 0.25f * 1.4426950408889634f * tm * sm;
}

// QKV projection, fp32 compute -> bf16 stores.
// Qb,Kb: [bh][l_pad][16] bf16;  VbT: [bh][d=16][l_pad] bf16.
__global__ __launch_bounds__(128) void qkv_proj_kernel(
    const float* __restrict__ x,
    const float* __restrict__ Wq, const float* __restrict__ bq,
    const float* __restrict__ Wk, const float* __restrict__ bk,
    const float* __restrict__ Wv, const float* __restrict__ bv,
    short* __restrict__ Qb, short* __restrict__ Kb, short* __restrict__ VbT)
{
    __shared__ float xs[16][D_MODEL];
    const int t = threadIdx.x;
    const int row0 = blockIdx.x * 16;
    const int b  = row0 / L_PAD;
    const int l0 = row0 - b * L_PAD;
    #pragma unroll
    for (int r = 0; r < 16; ++r) {
        int l = l0 + r;
        xs[r][t] = (l < L_TOTAL) ? x[((size_t)b * L_TOTAL + l) * D_MODEL + t] : 0.f;
    }
    __syncthreads();

    float aq[16], ak[16], av[16];
    #pragma unroll
    for (int r = 0; r < 16; ++r) { aq[r] = 0.f; ak[r] = 0.f; av[r] = 0.f; }

    for (int i = 0; i < D_MODEL; ++i) {
        float wq = Wq[i * D_MODEL + t];
        float wk = Wk[i * D_MODEL + t];
        float wv = Wv[i * D_MODEL + t];
        #pragma unroll
        for (int r = 0; r < 16; ++r) {
            float xv = xs[r][i];
            aq[r] += xv * wq;
            ak[r] += xv * wk;
            av[r] += xv * wv;
        }
    }

    const float bqv = bq[t], bkv = bk[t], bvv = bv[t];
    const int h = t >> 4, d = t & 15;
    const int bh = b * NUM_HEADS + h;

    #pragma unroll
    for (int r = 0; r < 16; ++r) {
        size_t o = ((size_t)bh * L_PAD + (l0 + r)) * DK + d;
        Qb[o] = (short)f2bf(aq[r] + bqv);
        Kb[o] = (short)f2bf(ak[r] + bkv);
    }
    {
        short* vp = VbT + ((size_t)bh * DK + d) * L_PAD + l0;
        unsigned* vp4 = (unsigned*)vp;
        #pragma unroll
        for (int j = 0; j < 8; ++j)
            vp4[j] = pk2bf(av[2 * j] + bvv, av[2 * j + 1] + bvv);
    }
}

// MFMA attention v3: block = 8 waves (512 thr). Wave w: q-tile (w>>1), key-half (w&1).
// Swapped QK^T (S^T = K*Q^T). Mask staged in LDS (54KB, stride-211), read via
// 4x ds_read_b32 with incremental nk counter. K/V: rotating 3-buffer depth-2
// register prefetch with running pointers. K-halves merged via LDS reuse.
__global__ __launch_bounds__(512, 6) void attn_mfma_kernel(
    const short* __restrict__ Qb, const short* __restrict__ Kb,
    const short* __restrict__ VbT, const float* __restrict__ msmN,
    float* __restrict__ Ctx)
{
    __shared__ float mlds[64 * MSTRIDE];   // mask slice; reused as merge scratch

    const int tid = threadIdx.x;
    const int l = tid & 63, w = tid >> 6;
    const int qt = w >> 1, kh = w & 1;
    const int r = l & 15, g = l >> 4;
    const int bh = blockIdx.y, b = bh >> 3, h = bh & 7;
    const int q0 = blockIdx.x * 64;
    const int q0w = q0 + qt * 16;

    // stage mask rows for this block's 64 queries: mlds[j][c] = msmN[(q0+j)%207][c%207]
    for (int i = tid; i < 64 * MSTRIDE; i += 512) {
        int j = i / MSTRIDE, c = i - j * MSTRIDE;
        int nq = (q0 + j) % NUM_NODES;
        int nk = (c >= NUM_NODES) ? c - NUM_NODES : c;
        mlds[i] = msmN[nq * NUM_NODES + nk];
    }

    const short* Kp = Kb + (size_t)bh * L_PAD * DK;
    const short* Vp = VbT + ((size_t)bh * DK + r) * L_PAD;

    int qload = q0w + r;
    if (qload > L_TOTAL - 1) qload = L_TOTAL - 1;          // clamp pad queries
    const v4s qf = *(const v4s*)(Qb + ((size_t)bh * L_PAD + qload) * DK + 4 * g);

    __syncthreads();                                       // mask slice ready

    const int kbase = kh * KHALF;
    const float* mrow = mlds + (qt * 16 + r) * MSTRIDE;
    int nkc = 6 * kh + 4 * g;                              // (kbase + 4g) % 207

    const short* kptr = Kp + (size_t)(kbase + r) * DK + 4 * g;
    const short* vptr = Vp + kbase + 4 * g;

    v4f ctx = {0.f, 0.f, 0.f, 0.f};
    float ss0 = 0.f, ss1 = 0.f, ss2 = 0.f, ss3 = 0.f;

#define LOADS(kf, vf, m0, m1, m2, m3) do {                                     \
    kf = *(const v4s*)kptr; kptr += 16 * DK;                                   \
    vf = *(const v4s*)vptr; vptr += 16;                                        \
    m0 = mrow[nkc]; m1 = mrow[nkc + 1];                                        \
    m2 = mrow[nkc + 2]; m3 = mrow[nkc + 3];                                    \
    nkc += 16; nkc = (nkc >= NUM_NODES) ? nkc - NUM_NODES : nkc;               \
} while (0)

#define COMPUTE(kf, vf, m0, m1, m2, m3, MASKED, KIDX) do {                     \
    v4f z = {0.f, 0.f, 0.f, 0.f};                                              \
    v4f sacc = MFMA16(kf, qf, z);                                              \
    float p0 = EXP2F(sacc[0] * m0);                                            \
    float p1 = EXP2F(sacc[1] * m1);                                            \
    float p2 = EXP2F(sacc[2] * m2);                                            \
    float p3 = EXP2F(sacc[3] * m3);                                            \
    if (MASKED) {                                                              \
        int kb0 = (KIDX) + 4 * g;                                              \
        if (kb0 + 0 >= L_TOTAL) p0 = 0.f;                                      \
        if (kb0 + 1 >= L_TOTAL) p1 = 0.f;                                      \
        if (kb0 + 2 >= L_TOTAL) p2 = 0.f;                                      \
        if (kb0 + 3 >= L_TOTAL) p3 = 0.f;                                      \
    }                                                                          \
    ss0 += p0; ss1 += p1; ss2 += p2; ss3 += p3;                                \
    unsigned plo = pk2bf(p0, p1);                                              \
    unsigned phi = pk2bf(p2, p3);                                              \
    v4s pf = __builtin_bit_cast(v4s, ((unsigned long long)phi << 32) | plo);   \
    ctx = MFMA16(pf, vf, ctx);                                                 \
} while (0)

    v4s kfA, vfA, kfB, vfB, kfC, vfC;
    float mA0, mA1, mA2, mA3, mB0, mB1, mB2, mB3, mC0, mC1, mC2, mC3;

    LOADS(kfA, vfA, mA0, mA1, mA2, mA3);                   // j=0
    LOADS(kfB, vfB, mB0, mB1, mB2, mB3);                   // j=1
    for (int t3 = 0; t3 < 25; ++t3) {                      // j = 3t .. 3t+2
        LOADS(kfC, vfC, mC0, mC1, mC2, mC3);
        COMPUTE(kfA, vfA, mA0, mA1, mA2, mA3, false, 0);
        LOADS(kfA, vfA, mA0, mA1, mA2, mA3);
        COMPUTE(kfB, vfB, mB0, mB1, mB2, mB3, false, 0);
        LOADS(kfB, vfB, mB0, mB1, mB2, mB3);
        COMPUTE(kfC, vfC, mC0, mC1, mC2, mC3, false, 0);
    }
    // consumed j=0..74; A holds j=75, B holds j=76
    LOADS(kfC, vfC, mC0, mC1, mC2, mC3);                   // j=77
    COMPUTE(kfA, vfA, mA0, mA1, mA2, mA3, false, 0);
    COMPUTE(kfB, vfB, mB0, mB1, mB2, mB3, false, 0);
    COMPUTE(kfC, vfC, mC0, mC1, mC2, mC3, kh, kbase + 1232);  // tail mask (kh=1 only)
#undef LOADS
#undef COMPUTE

    // intra-wave row sums: combine the 4 lane-groups -> uniform per r
    float s = (ss0 + ss1) + (ss2 + ss3);
    s += __shfl_xor(s, 16);
    s += __shfl_xor(s, 32);

    // merge the two key-halves via LDS reuse (mask slice no longer needed)
    __syncthreads();
    float* mg = mlds;                                      // [qt][l][5]
    if (kh == 1) {
        float* p = mg + (qt * 64 + l) * 5;
        p[0] = ctx[0]; p[1] = ctx[1]; p[2] = ctx[2]; p[3] = ctx[3]; p[4] = s;
    }
    __syncthreads();
    if (kh == 0) {
        const float* p = mg + (qt * 64 + l) * 5;
        ctx[0] += p[0]; ctx[1] += p[1]; ctx[2] += p[2]; ctx[3] += p[3];
        s += p[4];
        float inv = 1.0f / s;
        #pragma unroll
        for (int i = 0; i < 4; ++i) {
            int q = q0w + 4 * g + i;
            float iv = __shfl(inv, 4 * g + i);
            if (q < L_TOTAL)
                Ctx[((size_t)b * L_TOTAL + q) * D_MODEL + h * DK + r] = ctx[i] * iv;
        }
    }
}

// Output projection: context (9936x128) @ Wo + bo -> out (fp32)
__global__ __launch_bounds__(128) void out_proj_kernel(
    const float* __restrict__ ctxin,
    const float* __restrict__ Wo, const float* __restrict__ bo,
    float* __restrict__ out)
{
    __shared__ float xs[16][D_MODEL];
    const int t = threadIdx.x;
    const int row0 = blockIdx.x * 16;
    #pragma unroll
    for (int r = 0; r < 16; ++r)
        xs[r][t] = ctxin[(size_t)(row0 + r) * D_MODEL + t];
    __syncthreads();

    float acc[16];
    #pragma unroll
    for (int r = 0; r < 16; ++r) acc[r] = 0.f;

    for (int i = 0; i < D_MODEL; ++i) {
        float wv = Wo[i * D_MODEL + t];
        #pragma unroll
        for (int r = 0; r < 16; ++r) acc[r] += xs[r][i] * wv;
    }

    float bv = bo[t];
    #pragma unroll
    for (int r = 0; r < 16; ++r)
        out[(size_t)(row0 + r) * D_MODEL + t] = acc[r] + bv;
}

extern "C" void kernel_launch(void* const* d_in, const int* in_sizes, int n_in,
                              void* d_out, int out_size, void* d_ws, size_t ws_size,
                              hipStream_t stream) {
    const float* x     = (const float*)d_in[0];
    const float* Wq    = (const float*)d_in[1];
    const float* bq    = (const float*)d_in[2];
    const float* Wk    = (const float*)d_in[3];
    const float* bk    = (const float*)d_in[4];
    const float* Wv    = (const float*)d_in[5];
    const float* bv    = (const float*)d_in[6];
    const float* Wo    = (const float*)d_in[7];
    const float* bo    = (const float*)d_in[8];
    const float* tmask = (const float*)d_in[9];
    const float* smask = (const float*)d_in[10];
    float* out = (float*)d_out;

    // workspace layout (~13 MB)
    char* ws = (char*)d_ws;
    size_t o = 0;
    float* msmN = (float*)(ws + o); o += ((size_t)NUM_NODES * NUM_NODES * 4 + 255) & ~(size_t)255;
    const size_t qk_bytes = (size_t)BATCH * NUM_HEADS * L_PAD * DK * 2;          // 2,555,904
    short* Qb  = (short*)(ws + o); o += qk_bytes;
    short* Kb  = (short*)(ws + o); o += qk_bytes;
    short* VbT = (short*)(ws + o); o += qk_bytes;
    float* Ctx = (float*)(ws + o); o += (size_t)BL * D_MODEL * 4;                // 5,087,232
    (void)ws_size; (void)in_sizes; (void)n_in; (void)out_size;

    mask_prep_kernel<<<(NUM_NODES * NUM_NODES + 255) / 256, 256, 0, stream>>>(tmask, smask, msmN);
    qkv_proj_kernel<<<(BATCH * L_PAD) / 16, 128, 0, stream>>>(x, Wq, bq, Wk, bk, Wv, bv, Qb, Kb, VbT);
    attn_mfma_kernel<<<dim3(L_PAD / 64, BATCH * NUM_HEADS), 512, 0, stream>>>(Qb, Kb, VbT, msmN, Ctx);
    out_proj_kernel<<<BL / 16, 128, 0, stream>>>(Ctx, Wo, bo, out);
}

// Round 9
// 190.433 us; speedup vs baseline: 1.4433x; 1.0217x over previous
//
#include <hip/hip_runtime.h>
#include <math.h>

#define D_MODEL   128
#define NUM_HEADS 8
#define DK        16
#define NUM_NODES 207
#define SEQ_LEN   12
#define BATCH     4
#define L_TOTAL   (SEQ_LEN * NUM_NODES)   // 2484
#define L_PAD     2496                    // 39*64, 78*32
#define BL        (BATCH * L_TOTAL)       // 9936
#define KHALF     1248                    // L_PAD / 2
#define MSTRIDE   211                     // odd stride -> <=3-way LDS bank aliasing

typedef short v4s __attribute__((ext_vector_type(4)));
typedef float v4f __attribute__((ext_vector_type(4)));

// Device pass: real builtins. Host pass: inert stubs (parsed, never executed).
#if defined(__HIP_DEVICE_COMPILE__)
#define MFMA16(a, b, c) __builtin_amdgcn_mfma_f32_16x16x16bf16_1k(a, b, c, 0, 0, 0)
#if __has_builtin(__builtin_amdgcn_exp2f)
#define EXP2F(x) __builtin_amdgcn_exp2f(x)   // compiler-emitted v_exp_f32, hazards handled
#else
#define EXP2F(x) exp2f(x)
#endif
#else
#define MFMA16(a, b, c) (c)
#define EXP2F(x) (x)
#endif

// float -> bf16 (round to nearest even), pure bit ops (finite inputs only)
static __device__ __forceinline__ unsigned short f2bf(float f) {
    unsigned u = __builtin_bit_cast(unsigned, f);
    unsigned rnd = 0x7fffu + ((u >> 16) & 1u);
    return (unsigned short)((u + rnd) >> 16);
}
static __device__ __forceinline__ unsigned pk2bf(float a, float b) {
    return (unsigned)f2bf(a) | ((unsigned)f2bf(b) << 16);
}
// two f32 -> packed bf16x2 in ONE VOP3 (guide T12 recipe; plain VALU, no hazard).
// low half = first operand (matches pk2bf).
static __device__ __forceinline__ unsigned cvtpk_bf16(float lo, float hi) {
#if defined(__HIP_DEVICE_COMPILE__)
    unsigned r;
    asm("v_cvt_pk_bf16_f32 %0, %1, %2" : "=v"(r) : "v"(lo), "v"(hi));
    return r;
#else
    return pk2bf(lo, hi);
#endif
}

// msmN[nq][nk] = 0.25 * log2(e) * sigmoid(tm) * sigmoid(sm[nq][nk]) -- raw 207x207
__global__ void mask_prep_kernel(const float* __restrict__ tmask,
                                 const float* __restrict__ smask,
                                 float* __restrict__ msmN) {
    int idx = blockIdx.x * 256 + threadIdx.x;
    if (idx >= NUM_NODES * NUM_NODES) return;
    float tm = 1.0f / (1.0f + __expf(-tmask[0]));
    float sm = 1.0f / (1.0f + __expf(-smask[idx]));
    msmN[idx] = 0.25f * 1.4426950408889634f * tm * sm;
}

// QKV projection, fp32 compute -> bf16 stores.
// Qb,Kb: [bh][l_pad][16] bf16;  VbT: [bh][d=16][l_pad] bf16.
__global__ __launch_bounds__(128) void qkv_proj_kernel(
    const float* __restrict__ x,
    const float* __restrict__ Wq, const float* __restrict__ bq,
    const float* __restrict__ Wk, const float* __restrict__ bk,
    const float* __restrict__ Wv, const float* __restrict__ bv,
    short* __restrict__ Qb, short* __restrict__ Kb, short* __restrict__ VbT)
{
    __shared__ float xs[16][D_MODEL];
    const int t = threadIdx.x;
    const int row0 = blockIdx.x * 16;
    const int b  = row0 / L_PAD;
    const int l0 = row0 - b * L_PAD;
    #pragma unroll
    for (int r = 0; r < 16; ++r) {
        int l = l0 + r;
        xs[r][t] = (l < L_TOTAL) ? x[((size_t)b * L_TOTAL + l) * D_MODEL + t] : 0.f;
    }
    __syncthreads();

    float aq[16], ak[16], av[16];
    #pragma unroll
    for (int r = 0; r < 16; ++r) { aq[r] = 0.f; ak[r] = 0.f; av[r] = 0.f; }

    for (int i = 0; i < D_MODEL; ++i) {
        float wq = Wq[i * D_MODEL + t];
        float wk = Wk[i * D_MODEL + t];
        float wv = Wv[i * D_MODEL + t];
        #pragma unroll
        for (int r = 0; r < 16; ++r) {
            float xv = xs[r][i];
            aq[r] += xv * wq;
            ak[r] += xv * wk;
            av[r] += xv * wv;
        }
    }

    const float bqv = bq[t], bkv = bk[t], bvv = bv[t];
    const int h = t >> 4, d = t & 15;
    const int bh = b * NUM_HEADS + h;

    #pragma unroll
    for (int r = 0; r < 16; ++r) {
        size_t o = ((size_t)bh * L_PAD + (l0 + r)) * DK + d;
        Qb[o] = (short)f2bf(aq[r] + bqv);
        Kb[o] = (short)f2bf(ak[r] + bkv);
    }
    {
        short* vp = VbT + ((size_t)bh * DK + d) * L_PAD + l0;
        unsigned* vp4 = (unsigned*)vp;
        #pragma unroll
        for (int j = 0; j < 8; ++j)
            vp4[j] = pk2bf(av[2 * j] + bvv, av[2 * j + 1] + bvv);
    }
}

// MFMA attention v4: block = 8 waves (512 thr). Wave w: q-tile (w>>1), key-half (w&1).
// Swapped QK^T (S^T = K*Q^T). Mask staged in LDS (54KB, stride-211). K/V: rotating
// 3-buffer depth-2 register prefetch. Pack via v_cvt_pk_bf16_f32; exp via v_exp_f32.
__global__ __launch_bounds__(512, 6) void attn_mfma_kernel(
    const short* __restrict__ Qb, const short* __restrict__ Kb,
    const short* __restrict__ VbT, const float* __restrict__ msmN,
    float* __restrict__ Ctx)
{
    __shared__ float mlds[64 * MSTRIDE];   // mask slice; reused as merge scratch

    const int tid = threadIdx.x;
    const int l = tid & 63, w = tid >> 6;
    const int qt = w >> 1, kh = w & 1;
    const int r = l & 15, g = l >> 4;
    const int bh = blockIdx.y, b = bh >> 3, h = bh & 7;
    const int q0 = blockIdx.x * 64;
    const int q0w = q0 + qt * 16;

    // stage mask rows: 8 threads per row, no per-element div/mod.
    {
        int j = tid >> 3, c0 = tid & 7;
        int nq = (q0 + j) % NUM_NODES;
        const float* src = msmN + nq * NUM_NODES;
        float* dst = mlds + j * MSTRIDE;
        for (int c = c0; c < MSTRIDE; c += 8) {
            int nk = (c >= NUM_NODES) ? c - NUM_NODES : c;
            dst[c] = src[nk];
        }
    }

    const short* Kp = Kb + (size_t)bh * L_PAD * DK;
    const short* Vp = VbT + ((size_t)bh * DK + r) * L_PAD;

    int qload = q0w + r;
    if (qload > L_TOTAL - 1) qload = L_TOTAL - 1;          // clamp pad queries
    const v4s qf = *(const v4s*)(Qb + ((size_t)bh * L_PAD + qload) * DK + 4 * g);

    __syncthreads();                                       // mask slice ready

    const int kbase = kh * KHALF;
    const float* mrow = mlds + (qt * 16 + r) * MSTRIDE;
    int nkc = 6 * kh + 4 * g;                              // (kbase + 4g) % 207

    const short* kptr = Kp + (size_t)(kbase + r) * DK + 4 * g;
    const short* vptr = Vp + kbase + 4 * g;

    v4f ctx = {0.f, 0.f, 0.f, 0.f};
    float ss0 = 0.f, ss1 = 0.f, ss2 = 0.f, ss3 = 0.f;

#define LOADS(kf, vf, m0, m1, m2, m3) do {                                     \
    kf = *(const v4s*)kptr; kptr += 16 * DK;                                   \
    vf = *(const v4s*)vptr; vptr += 16;                                        \
    m0 = mrow[nkc]; m1 = mrow[nkc + 1];                                        \
    m2 = mrow[nkc + 2]; m3 = mrow[nkc + 3];                                    \
    nkc += 16; nkc = (nkc >= NUM_NODES) ? nkc - NUM_NODES : nkc;               \
} while (0)

#define COMPUTE(kf, vf, m0, m1, m2, m3, MASKED, KIDX) do {                     \
    v4f z = {0.f, 0.f, 0.f, 0.f};                                              \
    v4f sacc = MFMA16(kf, qf, z);                                              \
    float p0 = EXP2F(sacc[0] * m0);                                            \
    float p1 = EXP2F(sacc[1] * m1);                                            \
    float p2 = EXP2F(sacc[2] * m2);                                            \
    float p3 = EXP2F(sacc[3] * m3);                                            \
    if (MASKED) {                                                              \
        int kb0 = (KIDX) + 4 * g;                                              \
        if (kb0 + 0 >= L_TOTAL) p0 = 0.f;                                      \
        if (kb0 + 1 >= L_TOTAL) p1 = 0.f;                                      \
        if (kb0 + 2 >= L_TOTAL) p2 = 0.f;                                      \
        if (kb0 + 3 >= L_TOTAL) p3 = 0.f;                                      \
    }                                                                          \
    ss0 += p0; ss1 += p1; ss2 += p2; ss3 += p3;                                \
    unsigned plo = cvtpk_bf16(p0, p1);                                         \
    unsigned phi = cvtpk_bf16(p2, p3);                                         \
    v4s pf = __builtin_bit_cast(v4s, ((unsigned long long)phi << 32) | plo);   \
    ctx = MFMA16(pf, vf, ctx);                                                 \
} while (0)

    v4s kfA, vfA, kfB, vfB, kfC, vfC;
    float mA0, mA1, mA2, mA3, mB0, mB1, mB2, mB3, mC0, mC1, mC2, mC3;

    LOADS(kfA, vfA, mA0, mA1, mA2, mA3);                   // j=0
    LOADS(kfB, vfB, mB0, mB1, mB2, mB3);                   // j=1
    for (int t3 = 0; t3 < 25; ++t3) {                      // j = 3t .. 3t+2
        LOADS(kfC, vfC, mC0, mC1, mC2, mC3);
        COMPUTE(kfA, vfA, mA0, mA1, mA2, mA3, false, 0);
        LOADS(kfA, vfA, mA0, mA1, mA2, mA3);
        COMPUTE(kfB, vfB, mB0, mB1, mB2, mB3, false, 0);
        LOADS(kfB, vfB, mB0, mB1, mB2, mB3);
        COMPUTE(kfC, vfC, mC0, mC1, mC2, mC3, false, 0);
    }
    // consumed j=0..74; A holds j=75, B holds j=76
    LOADS(kfC, vfC, mC0, mC1, mC2, mC3);                   // j=77
    COMPUTE(kfA, vfA, mA0, mA1, mA2, mA3, false, 0);
    COMPUTE(kfB, vfB, mB0, mB1, mB2, mB3, false, 0);
    COMPUTE(kfC, vfC, mC0, mC1, mC2, mC3, kh, kbase + 1232);  // tail mask (kh=1 only)
#undef LOADS
#undef COMPUTE

    // intra-wave row sums: combine the 4 lane-groups -> uniform per r
    float s = (ss0 + ss1) + (ss2 + ss3);
    s += __shfl_xor(s, 16);
    s += __shfl_xor(s, 32);

    // merge the two key-halves via LDS reuse (mask slice no longer needed)
    __syncthreads();
    float* mg = mlds;                                      // [qt][l][5]
    if (kh == 1) {
        float* p = mg + (qt * 64 + l) * 5;
        p[0] = ctx[0]; p[1] = ctx[1]; p[2] = ctx[2]; p[3] = ctx[3]; p[4] = s;
    }
    __syncthreads();
    if (kh == 0) {
        const float* p = mg + (qt * 64 + l) * 5;
        ctx[0] += p[0]; ctx[1] += p[1]; ctx[2] += p[2]; ctx[3] += p[3];
        s += p[4];
        float inv = 1.0f / s;
        #pragma unroll
        for (int i = 0; i < 4; ++i) {
            int q = q0w + 4 * g + i;
            float iv = __shfl(inv, 4 * g + i);
            if (q < L_TOTAL)
                Ctx[((size_t)b * L_TOTAL + q) * D_MODEL + h * DK + r] = ctx[i] * iv;
        }
    }
}

// Output projection: context (9936x128) @ Wo + bo -> out (fp32)
__global__ __launch_bounds__(128) void out_proj_kernel(
    const float* __restrict__ ctxin,
    const float* __restrict__ Wo, const float* __restrict__ bo,
    float* __restrict__ out)
{
    __shared__ float xs[16][D_MODEL];
    const int t = threadIdx.x;
    const int row0 = blockIdx.x * 16;
    #pragma unroll
    for (int r = 0; r < 16; ++r)
        xs[r][t] = ctxin[(size_t)(row0 + r) * D_MODEL + t];
    __syncthreads();

    float acc[16];
    #pragma unroll
    for (int r = 0; r < 16; ++r) acc[r] = 0.f;

    for (int i = 0; i < D_MODEL; ++i) {
        float wv = Wo[i * D_MODEL + t];
        #pragma unroll
        for (int r = 0; r < 16; ++r) acc[r] += xs[r][i] * wv;
    }

    float bv = bo[t];
    #pragma unroll
    for (int r = 0; r < 16; ++r)
        out[(size_t)(row0 + r) * D_MODEL + t] = acc[r] + bv;
}

extern "C" void kernel_launch(void* const* d_in, const int* in_sizes, int n_in,
                              void* d_out, int out_size, void* d_ws, size_t ws_size,
                              hipStream_t stream) {
    const float* x     = (const float*)d_in[0];
    const float* Wq    = (const float*)d_in[1];
    const float* bq    = (const float*)d_in[2];
    const float* Wk    = (const float*)d_in[3];
    const float* bk    = (const float*)d_in[4];
    const float* Wv    = (const float*)d_in[5];
    const float* bv    = (const float*)d_in[6];
    const float* Wo    = (const float*)d_in[7];
    const float* bo    = (const float*)d_in[8];
    const float* tmask = (const float*)d_in[9];
    const float* smask = (const float*)d_in[10];
    float* out = (float*)d_out;

    // workspace layout (~13 MB)
    char* ws = (char*)d_ws;
    size_t o = 0;
    float* msmN = (float*)(ws + o); o += ((size_t)NUM_NODES * NUM_NODES * 4 + 255) & ~(size_t)255;
    const size_t qk_bytes = (size_t)BATCH * NUM_HEADS * L_PAD * DK * 2;          // 2,555,904
    short* Qb  = (short*)(ws + o); o += qk_bytes;
    short* Kb  = (short*)(ws + o); o += qk_bytes;
    short* VbT = (short*)(ws + o); o += qk_bytes;
    float* Ctx = (float*)(ws + o); o += (size_t)BL * D_MODEL * 4;                // 5,087,232
    (void)ws_size; (void)in_sizes; (void)n_in; (void)out_size;

    mask_prep_kernel<<<(NUM_NODES * NUM_NODES + 255) / 256, 256, 0, stream>>>(tmask, smask, msmN);
    qkv_proj_kernel<<<(BATCH * L_PAD) / 16, 128, 0, stream>>>(x, Wq, bq, Wk, bk, Wv, bv, Qb, Kb, VbT);
    attn_mfma_kernel<<<dim3(L_PAD / 64, BATCH * NUM_HEADS), 512, 0, stream>>>(Qb, Kb, VbT, msmN, Ctx);
    out_proj_kernel<<<BL / 16, 128, 0, stream>>>(Ctx, Wo, bo, out);
}